// Round 3
// baseline (389.091 us; speedup 1.0000x reference)
//
#include <hip/hip_runtime.h>
#include <hip/hip_bf16.h>

// DecoderConv: weighted conv1d (B=8, Cin=Cout=256, L=16384, K=9) + BatchNorm(train) + ReLU
// y[b,o,l] = sum_{c,kk} W[o,c,kk] * x[b,c,l+kk-4] * w[b,kk,l]
// Round-3 structure (same verified index maps as round-2 PASS):
//   - A-frags loaded DIRECT from global (L2-resident Aperm) -> no Ash, no per-kk barriers
//   - x held in packed-bf16 regs, staged to Xsh once per 64c-chunk (2 barriers/chunk)
//   - next-chunk x loads issued at compute start (latency hidden under 9kk of MFMA)
//   - v_cvt_pk_bf16_f32 for all f32->bf16 packing (B-frag weight-repack + x pack)

typedef float        f32x4  __attribute__((ext_vector_type(4)));
typedef short        bf16x8 __attribute__((ext_vector_type(8)));
typedef unsigned int u32x2  __attribute__((ext_vector_type(2)));
typedef unsigned int u32x4  __attribute__((ext_vector_type(4)));

#define LLEN 16384

__device__ __forceinline__ unsigned short bf16bits(float a) {
  return __builtin_bit_cast(unsigned short, __float2bfloat16(a));
}
__device__ __forceinline__ unsigned cvt_pk_bf16(float lo, float hi) {
  unsigned r;
  asm("v_cvt_pk_bf16_f32 %0, %1, %2" : "=v"(r) : "v"(lo), "v"(hi));
  return r;
}

// ================= k_prep: Aperm[kk][o][c] + zero sums =================
__global__ void k_prep(const float* __restrict__ cw,
                       unsigned short* __restrict__ Aperm,
                       float* __restrict__ sums) {
  const int idx = blockIdx.x * 256 + threadIdx.x;  // 2304*256 = 256*256*9 exactly
  if (idx < 512) sums[idx] = 0.0f;
  const int o   = idx / 2304;
  const int rem = idx - o * 2304;
  const int c   = rem / 9;
  const int kk  = rem - c * 9;
  Aperm[((size_t)kk * 256 + o) * 256 + c] = bf16bits(cw[idx]);
}

// ================= k_w: gaussian weights w[b][kk][l] =================
__global__ void k_w(const float* __restrict__ coords, float* __restrict__ wbuf) {
  const int gidx = blockIdx.x * 256 + threadIdx.x;  // = b*L + l
  const int b = gidx >> 14, l = gidx & (LLEN - 1);
  const float* cb = coords + (size_t)b * 3 * LLEN;
  const float c0 = cb[l], c1 = cb[LLEN + l], c2v = cb[2 * LLEN + l];
#pragma unroll
  for (int kk = 0; kk < 9; ++kk) {
    const int lc = l + kk - 4;
    float a0 = 0.f, a1 = 0.f, a2 = 0.f;
    if (lc >= 0 && lc < LLEN) { a0 = cb[lc]; a1 = cb[LLEN + lc]; a2 = cb[2 * LLEN + lc]; }
    const float d0 = a0 - c0, d1 = a1 - c1, d2 = a2 - c2v;
    wbuf[(((size_t)(b * 9 + kk)) << 14) + l] = __expf(-0.5f * (d0 * d0 + d1 * d1 + d2 * d2));
  }
}

// ================= k_gemm =================
__global__ __launch_bounds__(512, 2) void k_gemm(
    const float* __restrict__ x, const float* __restrict__ wbuf,
    const unsigned short* __restrict__ Aperm, const float* __restrict__ convb,
    float* __restrict__ y, float* __restrict__ sums) {
  __shared__ __align__(16) unsigned short Xsh[264][72];  // x^T tile [l'][c], pad->144B rows

  const int tid  = threadIdx.x;
  const int lane = tid & 63, wv = tid >> 6;
  const int wm = wv >> 2, wn = wv & 3;          // 2 x 4 waves
  const int hi = lane >> 4, lo16 = lane & 15;
  const int b  = blockIdx.x >> 6, lt = blockIdx.x & 63;
  const int l0 = lt << 8;
  const int nbase = wn * 64 + lo16;

  f32x4 acc[8][4];
#pragma unroll
  for (int i = 0; i < 8; ++i)
#pragma unroll
    for (int j = 0; j < 4; ++j) acc[i][j] = f32x4{0.f, 0.f, 0.f, 0.f};

  // x staging: thread owns column c = tid>>3, row-groups grp = (tid&7) + 8*i
  const int c = tid >> 3, rg = tid & 7;
  u32x2 xp[9];  // packed bf16, 4 rows per entry

  auto loadx = [&](int cc) {
    const float* xrow = x + ((size_t)(b * 256 + cc * 64 + c)) * LLEN;
#pragma unroll
    for (int i = 0; i < 9; ++i) {
      const int grp = rg + 8 * i;
      f32x4 v = {0.f, 0.f, 0.f, 0.f};
      const int lx = l0 - 4 + grp * 4;  // always 4-aligned: OOB is all-or-nothing
      if (grp < 66 && lx >= 0 && lx <= LLEN - 4)
        v = *reinterpret_cast<const f32x4*>(xrow + lx);
      xp[i][0] = cvt_pk_bf16(v[0], v[1]);
      xp[i][1] = cvt_pk_bf16(v[2], v[3]);
    }
  };
  auto storex = [&]() {
#pragma unroll
    for (int i = 0; i < 9; ++i) {
      const int grp = rg + 8 * i;
      if (grp < 66) {
        const int r = grp * 4;
        Xsh[r + 0][c] = (unsigned short)(xp[i][0] & 0xffffu);
        Xsh[r + 1][c] = (unsigned short)(xp[i][0] >> 16);
        Xsh[r + 2][c] = (unsigned short)(xp[i][1] & 0xffffu);
        Xsh[r + 3][c] = (unsigned short)(xp[i][1] >> 16);
      }
    }
  };

  loadx(0);
#pragma unroll 1
  for (int cc = 0; cc < 4; ++cc) {
    if (cc) __syncthreads();   // all reads of Xsh done (prev chunk)
    storex();
    __syncthreads();           // staging visible
    if (cc < 3) loadx(cc + 1); // issue next chunk's x loads early (T14)

#pragma unroll 1
    for (int kk = 0; kk < 9; ++kk) {
      float wl[4];
#pragma unroll
      for (int nt = 0; nt < 4; ++nt)
        wl[nt] = wbuf[((size_t)(b * 9 + kk) << 14) + l0 + nbase + nt * 16];
      const unsigned short* Abase =
          Aperm + ((size_t)kk * 256 + wm * 128 + lo16) * 256 + cc * 64 + hi * 8;

#pragma unroll
      for (int kb = 0; kb < 2; ++kb) {
        // A-frags direct from global/L2 (same values Ash held in round 2)
        u32x4 ag[8];
#pragma unroll
        for (int mt = 0; mt < 8; ++mt)
          ag[mt] = *reinterpret_cast<const u32x4*>(Abase + mt * 16 * 256 + kb * 32);
        // B-frags: Xsh read + per-lane gaussian weight, cvt_pk repack
        bf16x8 bf[4];
#pragma unroll
        for (int nt = 0; nt < 4; ++nt) {
          const int r = nbase + nt * 16 + kk;
          const u32x4 xv = *reinterpret_cast<const u32x4*>(
              reinterpret_cast<const char*>(&Xsh[0][0]) + r * 144 + kb * 64 + hi * 16);
          const float wv2 = wl[nt];
          u32x4 o4;
#pragma unroll
          for (int q = 0; q < 4; ++q) {
            const float flo = __builtin_bit_cast(float, xv[q] << 16) * wv2;
            const float fhi = __builtin_bit_cast(float, xv[q] & 0xffff0000u) * wv2;
            o4[q] = cvt_pk_bf16(flo, fhi);
          }
          bf[nt] = __builtin_bit_cast(bf16x8, o4);
        }
        // MFMA cluster
#pragma unroll
        for (int mt = 0; mt < 8; ++mt) {
          const bf16x8 af = __builtin_bit_cast(bf16x8, ag[mt]);
#pragma unroll
          for (int nt = 0; nt < 4; ++nt)
            acc[mt][nt] = __builtin_amdgcn_mfma_f32_16x16x32_bf16(af, bf[nt],
                                                                  acc[mt][nt], 0, 0, 0);
        }
      }
    }
  }

  // ---- epilogue: +conv_b, raw y store, per-channel sums ----
  __syncthreads();
  float* red = reinterpret_cast<float*>(&Xsh[0][0]);  // 512 floats
  red[tid] = 0.0f;
  __syncthreads();
#pragma unroll
  for (int mt = 0; mt < 8; ++mt) {
#pragma unroll
    for (int v = 0; v < 4; ++v) {
      const int o = wm * 128 + mt * 16 + hi * 4 + v;  // C/D: row = hi*4 + reg
      const float cb = convb[o];
      float s = 0.f, s2 = 0.f;
#pragma unroll
      for (int nt = 0; nt < 4; ++nt) {
        const int l = l0 + nbase + nt * 16;           // C/D: col = lo16
        const float yv = acc[mt][nt][v] + cb;
        y[(((size_t)b * 256 + o) << 14) + l] = yv;
        s += yv; s2 += yv * yv;
      }
#pragma unroll
      for (int d = 1; d < 16; d <<= 1) { s += __shfl_xor(s, d); s2 += __shfl_xor(s2, d); }
      if (lo16 == 0) { atomicAdd(&red[o], s); atomicAdd(&red[o + 256], s2); }
    }
  }
  __syncthreads();
  atomicAdd(&sums[tid], red[tid]);
}

// ================= k_norm: batchnorm + relu, in place on d_out =================
__global__ void k_norm(float* __restrict__ y, const float* __restrict__ sums,
                       const float* __restrict__ gamma, const float* __restrict__ beta) {
  const size_t i0 = ((size_t)blockIdx.x * 256 + threadIdx.x) * 8;
  const int o = (int)((i0 >> 14) & 255);
  const float n = 131072.f;  // B*L
  const float mu = sums[o] / n;
  float var = sums[256 + o] / n - mu * mu;
  var = fmaxf(var, 0.f);
  const float sc = rsqrtf(var + 1e-5f) * gamma[o];
  const float bb = beta[o] - mu * sc;
  f32x4 v0 = *reinterpret_cast<const f32x4*>(y + i0);
  f32x4 v1 = *reinterpret_cast<const f32x4*>(y + i0 + 4);
#pragma unroll
  for (int i = 0; i < 4; ++i) {
    v0[i] = fmaxf(v0[i] * sc + bb, 0.f);
    v1[i] = fmaxf(v1[i] * sc + bb, 0.f);
  }
  *reinterpret_cast<f32x4*>(y + i0) = v0;
  *reinterpret_cast<f32x4*>(y + i0 + 4) = v1;
}

// ================= launch =================
extern "C" void kernel_launch(void* const* d_in, const int* in_sizes, int n_in,
                              void* d_out, int out_size, void* d_ws, size_t ws_size,
                              hipStream_t stream) {
  const float* x      = (const float*)d_in[0];
  const float* coords = (const float*)d_in[1];
  const float* conv_w = (const float*)d_in[2];
  const float* conv_b = (const float*)d_in[3];
  const float* gamma  = (const float*)d_in[4];
  const float* beta   = (const float*)d_in[5];
  float* out = (float*)d_out;

  float* sums = (float*)d_ws;                          // 512 f32
  float* wbuf = (float*)((char*)d_ws + 4096);          // 8*9*16384 f32 = 4.72MB
  unsigned short* Aperm =
      (unsigned short*)((char*)d_ws + 4096 + (size_t)8 * 9 * LLEN * 4);  // 9*256*256 bf16

  k_prep<<<2304, 256, 0, stream>>>(conv_w, Aperm, sums);
  k_w<<<512, 256, 0, stream>>>(coords, wbuf);
  k_gemm<<<512, 512, 0, stream>>>(x, wbuf, Aperm, conv_b, out, sums);
  k_norm<<<16384, 256, 0, stream>>>(out, sums, gamma, beta);
}

// Round 4
// 246.955 us; speedup vs baseline: 1.5756x; 1.5756x over previous
//
#include <hip/hip_runtime.h>
#include <hip/hip_bf16.h>

// DecoderConv: weighted conv1d (B=8, Cin=Cout=256, L=16384, K=9) + BatchNorm(train) + ReLU
// y[b,o,l] = sum_{c,kk} W[o,c,kk] * x[b,c,l+kk-4] * w[b,kk,l]
// Round-4: r2's verified index maps + pipelined double-buffered LDS schedule:
//   - Ash[2] 256x64 bf16 (XOR-swizzled units), staged regs->LDS one kk ahead
//   - Xsh[2] 264x72 bf16 (x^T, padded rows), next chunk streamed 1 piece/kk
//   - ONE barrier per kk; A/w/x loads issued early, consumed late (counted vmcnt)
//   - B-frag: Xsh b128 read + per-lane gaussian w, f32x2 mul + v_cvt_pk_bf16_f32

typedef float        f32x4  __attribute__((ext_vector_type(4)));
typedef float        f32x2  __attribute__((ext_vector_type(2)));
typedef short        bf16x8 __attribute__((ext_vector_type(8)));
typedef unsigned int u32x4  __attribute__((ext_vector_type(4)));

#define LLEN 16384

__device__ __forceinline__ unsigned short bf16bits(float a) {
  return __builtin_bit_cast(unsigned short, __float2bfloat16(a));
}
__device__ __forceinline__ unsigned cvt_pk_bf16(float lo, float hi) {
  unsigned r;
  asm("v_cvt_pk_bf16_f32 %0, %1, %2" : "=v"(r) : "v"(lo), "v"(hi));
  return r;
}

// ================= k_prep: Aperm[kk][o][c] + zero sums =================
__global__ void k_prep(const float* __restrict__ cw,
                       unsigned short* __restrict__ Aperm,
                       float* __restrict__ sums) {
  const int idx = blockIdx.x * 256 + threadIdx.x;  // 2304*256 = 256*256*9 exactly
  if (idx < 512) sums[idx] = 0.0f;
  const int o   = idx / 2304;
  const int rem = idx - o * 2304;
  const int c   = rem / 9;
  const int kk  = rem - c * 9;
  Aperm[((size_t)kk * 256 + o) * 256 + c] = bf16bits(cw[idx]);
}

// ================= k_w: gaussian weights w[b][kk][l] =================
__global__ void k_w(const float* __restrict__ coords, float* __restrict__ wbuf) {
  const int gidx = blockIdx.x * 256 + threadIdx.x;  // = b*L + l
  const int b = gidx >> 14, l = gidx & (LLEN - 1);
  const float* cb = coords + (size_t)b * 3 * LLEN;
  const float c0 = cb[l], c1 = cb[LLEN + l], c2v = cb[2 * LLEN + l];
#pragma unroll
  for (int kk = 0; kk < 9; ++kk) {
    const int lc = l + kk - 4;
    float a0 = 0.f, a1 = 0.f, a2 = 0.f;
    if (lc >= 0 && lc < LLEN) { a0 = cb[lc]; a1 = cb[LLEN + lc]; a2 = cb[2 * LLEN + lc]; }
    const float d0 = a0 - c0, d1 = a1 - c1, d2 = a2 - c2v;
    wbuf[(((size_t)(b * 9 + kk)) << 14) + l] = __expf(-0.5f * (d0 * d0 + d1 * d1 + d2 * d2));
  }
}

// ================= k_gemm =================
__global__ __launch_bounds__(512, 2) void k_gemm(
    const float* __restrict__ x, const float* __restrict__ wbuf,
    const unsigned short* __restrict__ Aperm, const float* __restrict__ convb,
    float* __restrict__ y, float* __restrict__ sums) {
  __shared__ __align__(16) unsigned short Ash[2][256 * 64];  // [o][c-unit swizzled], 32KB each
  __shared__ __align__(16) unsigned short Xsh[2][264 * 72];  // x^T [l'][c], 144B rows, 38KB each

  const int tid  = threadIdx.x;
  const int lane = tid & 63, wv = tid >> 6;
  const int wm = wv >> 2, wn = wv & 3;          // 2 x 4 waves
  const int hi = lane >> 4, lo16 = lane & 15;
  const int b  = blockIdx.x >> 6, lt = blockIdx.x & 63;
  const int l0 = lt << 8;
  const int nbase = wn * 64 + lo16;
  const int c = tid >> 3, rg = tid & 7;         // x-staging: column + row-group

  f32x4 acc[8][4];
#pragma unroll
  for (int i = 0; i < 8; ++i)
#pragma unroll
    for (int j = 0; j < 4; ++j) acc[i][j] = f32x4{0.f, 0.f, 0.f, 0.f};

  // ---- helpers ----
  auto loadA = [&](int kk, int cc, u32x4 (&dst)[4]) {
#pragma unroll
    for (int p = 0; p < 4; ++p) {
      const int row = p * 64 + (tid >> 3);
      dst[p] = *reinterpret_cast<const u32x4*>(
          Aperm + ((size_t)kk * 256 + row) * 256 + cc * 64 + ((tid & 7) << 3));
    }
  };
  auto writeA = [&](int ab, const u32x4 (&src)[4]) {
#pragma unroll
    for (int p = 0; p < 4; ++p) {
      const int row  = p * 64 + (tid >> 3);
      const unsigned byte = (unsigned)(row * 128 + (((tid & 7) ^ (row & 7)) << 4));
      *reinterpret_cast<u32x4*>(reinterpret_cast<char*>(&Ash[ab][0]) + byte) = src[p];
    }
  };
  auto loadPiece = [&](int ncc, int i) -> f32x4 {
    const float* xrow = x + ((size_t)(b * 256 + ncc * 64 + c)) * LLEN;
    const int grp = rg + 8 * i;
    const int lx = l0 - 4 + grp * 4;
    f32x4 v = {0.f, 0.f, 0.f, 0.f};
    if (grp < 66 && lx >= 0 && lx <= LLEN - 4)
      v = *reinterpret_cast<const f32x4*>(xrow + lx);
    return v;
  };
  auto writePiece = [&](int xb, int i, const f32x4& v) {
    const int grp = rg + 8 * i;
    if (grp < 66) {
      unsigned short* base = &Xsh[xb][0] + (grp * 4) * 72 + c;
      base[0]   = bf16bits(v[0]);
      base[72]  = bf16bits(v[1]);
      base[144] = bf16bits(v[2]);
      base[216] = bf16bits(v[3]);
    }
  };

  // ---- prologue: stage A(0,0) -> Ash[0], X(cc=0) -> Xsh[0] ----
  {
    u32x4 a0[4];
    loadA(0, 0, a0);
    writeA(0, a0);
#pragma unroll
    for (int i = 0; i < 9; ++i) writePiece(0, i, loadPiece(0, i));
  }
  float wl[4];
#pragma unroll
  for (int nt = 0; nt < 4; ++nt)
    wl[nt] = wbuf[((size_t)(b * 9) << 14) + l0 + nbase + nt * 16];
  __syncthreads();

  int ab = 0;
  f32x4 xhold = {0.f, 0.f, 0.f, 0.f};

#pragma unroll 1
  for (int cc = 0; cc < 4; ++cc) {
    const int xb = cc & 1;
#pragma unroll 1
    for (int kk = 0; kk < 9; ++kk) {
      const int nkk = (kk == 8) ? 0 : kk + 1;
      const int ncc = (kk == 8) ? cc + 1 : cc;
      const bool has_next = (ncc < 4);

      // 1. issue next step's A loads (consumed at end of this kk)
      u32x4 areg[4];
      if (has_next) loadA(nkk, ncc, areg);
      // 2. issue next step's w loads
      float wln[4] = {0.f, 0.f, 0.f, 0.f};
      if (has_next) {
#pragma unroll
        for (int nt = 0; nt < 4; ++nt)
          wln[nt] = wbuf[((size_t)(b * 9 + nkk) << 14) + l0 + nbase + nt * 16];
      }
      // 3. issue x piece kk of chunk cc+1 (written next kk)
      f32x4 xnew = {0.f, 0.f, 0.f, 0.f};
      if (cc < 3) xnew = loadPiece(cc + 1, kk);

      // 4/5. compute: 2 kb halves, reads Ash[ab] + Xsh[xb]
      const char* AshB = reinterpret_cast<const char*>(&Ash[ab][0]);
      const char* XshB = reinterpret_cast<const char*>(&Xsh[xb][0]);
#pragma unroll
      for (int kb = 0; kb < 2; ++kb) {
        bf16x8 bfr[4];
#pragma unroll
        for (int nt = 0; nt < 4; ++nt) {
          const int r = nbase + nt * 16 + kk;
          const u32x4 xv = *reinterpret_cast<const u32x4*>(XshB + r * 144 + kb * 64 + hi * 16);
          const float wv2 = wl[nt];
          u32x4 o4;
#pragma unroll
          for (int q = 0; q < 4; ++q) {
            f32x2 f = {__builtin_bit_cast(float, xv[q] << 16),
                       __builtin_bit_cast(float, xv[q] & 0xffff0000u)};
            f *= wv2;
            o4[q] = cvt_pk_bf16(f[0], f[1]);
          }
          bfr[nt] = __builtin_bit_cast(bf16x8, o4);
        }
#pragma unroll
        for (int mt = 0; mt < 8; ++mt) {
          const int orow = wm * 128 + mt * 16 + lo16;
          const unsigned aoff = (unsigned)(orow * 128 + (((kb * 4 + hi) ^ (orow & 7)) << 4));
          const bf16x8 af = *reinterpret_cast<const bf16x8*>(AshB + aoff);
#pragma unroll
          for (int nt = 0; nt < 4; ++nt)
            acc[mt][nt] = __builtin_amdgcn_mfma_f32_16x16x32_bf16(af, bfr[nt],
                                                                  acc[mt][nt], 0, 0, 0);
        }
      }

      // 6. write x piece(s) into the idle X buffer
      if (cc < 3 && kk >= 1) writePiece(xb ^ 1, kk - 1, xhold);
      if (cc < 3 && kk == 8) writePiece(xb ^ 1, 8, xnew);
      // 7. write next A into the idle A buffer
      if (has_next) writeA(ab ^ 1, areg);

      __syncthreads();
      ab ^= 1;
      xhold = xnew;
#pragma unroll
      for (int nt = 0; nt < 4; ++nt) wl[nt] = wln[nt];
    }
  }

  // ---- epilogue: +conv_b, raw y store, per-channel sums ----
  float* red = reinterpret_cast<float*>(&Ash[0][0]);  // 512 floats
  red[tid] = 0.0f;
  __syncthreads();
#pragma unroll
  for (int mt = 0; mt < 8; ++mt) {
#pragma unroll
    for (int v = 0; v < 4; ++v) {
      const int o = wm * 128 + mt * 16 + hi * 4 + v;  // C/D: row = hi*4 + reg
      const float cb = convb[o];
      float s = 0.f, s2 = 0.f;
#pragma unroll
      for (int nt = 0; nt < 4; ++nt) {
        const int l = l0 + nbase + nt * 16;           // C/D: col = lo16
        const float yv = acc[mt][nt][v] + cb;
        y[(((size_t)b * 256 + o) << 14) + l] = yv;
        s += yv; s2 += yv * yv;
      }
#pragma unroll
      for (int d = 1; d < 16; d <<= 1) { s += __shfl_xor(s, d); s2 += __shfl_xor(s2, d); }
      if (lo16 == 0) { atomicAdd(&red[o], s); atomicAdd(&red[o + 256], s2); }
    }
  }
  __syncthreads();
  atomicAdd(&sums[tid], red[tid]);
}

// ================= k_norm: batchnorm + relu, in place on d_out =================
__global__ void k_norm(float* __restrict__ y, const float* __restrict__ sums,
                       const float* __restrict__ gamma, const float* __restrict__ beta) {
  const size_t i0 = ((size_t)blockIdx.x * 256 + threadIdx.x) * 8;
  const int o = (int)((i0 >> 14) & 255);
  const float n = 131072.f;  // B*L
  const float mu = sums[o] / n;
  float var = sums[256 + o] / n - mu * mu;
  var = fmaxf(var, 0.f);
  const float sc = rsqrtf(var + 1e-5f) * gamma[o];
  const float bb = beta[o] - mu * sc;
  f32x4 v0 = *reinterpret_cast<const f32x4*>(y + i0);
  f32x4 v1 = *reinterpret_cast<const f32x4*>(y + i0 + 4);
#pragma unroll
  for (int i = 0; i < 4; ++i) {
    v0[i] = fmaxf(v0[i] * sc + bb, 0.f);
    v1[i] = fmaxf(v1[i] * sc + bb, 0.f);
  }
  *reinterpret_cast<f32x4*>(y + i0) = v0;
  *reinterpret_cast<f32x4*>(y + i0 + 4) = v1;
}

// ================= launch =================
extern "C" void kernel_launch(void* const* d_in, const int* in_sizes, int n_in,
                              void* d_out, int out_size, void* d_ws, size_t ws_size,
                              hipStream_t stream) {
  const float* x      = (const float*)d_in[0];
  const float* coords = (const float*)d_in[1];
  const float* conv_w = (const float*)d_in[2];
  const float* conv_b = (const float*)d_in[3];
  const float* gamma  = (const float*)d_in[4];
  const float* beta   = (const float*)d_in[5];
  float* out = (float*)d_out;

  float* sums = (float*)d_ws;                          // 512 f32
  float* wbuf = (float*)((char*)d_ws + 4096);          // 8*9*16384 f32 = 4.72MB
  unsigned short* Aperm =
      (unsigned short*)((char*)d_ws + 4096 + (size_t)8 * 9 * LLEN * 4);  // 9*256*256 bf16

  k_prep<<<2304, 256, 0, stream>>>(conv_w, Aperm, sums);
  k_w<<<512, 256, 0, stream>>>(coords, wbuf);
  k_gemm<<<512, 512, 0, stream>>>(x, wbuf, Aperm, conv_b, out, sums);
  k_norm<<<16384, 256, 0, stream>>>(out, sums, gamma, beta);
}